// Round 3
// baseline (267.228 us; speedup 1.0000x reference)
//
#include <hip/hip_runtime.h>
#include <stdint.h>

// Q4_0 dequant-GEMM: y[t,o] = sum_k x[t,k] * s[o,k/32]*(q[o,k]-8) + bias[o]
// M=16 tokens, K=4096, N=11008. HBM-bound on the 172 MiB int32 qweight read
// (floor ~29 us at 6.3 TB/s).
//
// R3: SINGLE kernel, no workspace, no atomics, no prep/zero-init.
//  - 688 blocks, one per 16-output MFMA tile; block owns full K.
//  - 4 waves x 32 quant-blocks (mfma_f32_16x16x32_bf16; K=32 == one Q4_0
//    block, so one scale per lane per MFMA).
//  - x (fp32, 256 KB, L2-hot) converted to bf16 A-fragments in registers
//    each iteration (round-half-up + v_perm pack) - removes the prep kernel
//    and its graph-node serialization.
//  - qweight loads nontemporal (streamed once; keep L2 for x/scales).
//  - Epilogue: LDS combine of the 4 partial K-sums, + bias, plain store.
//    Removes 704k agent-scope atomicAdds of R2.

typedef __attribute__((ext_vector_type(8))) short bf16x8;  // 8 bf16 (4 VGPRs)
typedef __attribute__((ext_vector_type(4))) float f32x4;   // mfma accumulator
typedef __attribute__((ext_vector_type(4))) int   i32x4;

#define OUT_F 11008
#define IN_F  4096
#define NB    128   // quant blocks along K (32 elements each)

__global__ __launch_bounds__(256) void qgemm_kernel(const float* __restrict__ x,
                                                    const int* __restrict__ qw,
                                                    const float* __restrict__ scales,
                                                    const float* __restrict__ bias,
                                                    float* __restrict__ out) {
  const int ob   = blockIdx.x << 4;   // 16 output features per block
  const int tid  = threadIdx.x;
  const int wave = tid >> 6;
  const int lane = tid & 63;
  const int col  = lane & 15;         // output row (B) / token (A) selector
  const int kr   = lane >> 4;         // k sub-chunk 0..3

  const int kb0 = wave * 32;          // this wave's 32 quant-blocks

  // per-lane bases
  const int*   qbase = qw + (size_t)(ob + col) * IN_F + kb0 * 32 + kr * 8;
  const float* xbase = x + col * IN_F + kb0 * 32 + kr * 8;   // L2-hot
  const float* sbase = scales + (ob + col) * NB + kb0;

  f32x4 acc = {0.f, 0.f, 0.f, 0.f};

  for (int o8 = 0; o8 < 4; ++o8) {            // 4 chunks of 8 quant-blocks
    f32x4 sA = *(const f32x4*)(sbase + o8 * 8);
    f32x4 sB = *(const f32x4*)(sbase + o8 * 8 + 4);
#pragma unroll
    for (int i = 0; i < 8; ++i) {
      const int ii = o8 * 8 + i;
      // B source: 8 int32 quants from this lane's output row (32B, part of a
      // 128B contiguous segment per row across the 4 kr lanes). Streamed once.
      const i32x4* qp = (const i32x4*)(qbase + ii * 32);
      i32x4 q0 = __builtin_nontemporal_load(qp);
      i32x4 q1 = __builtin_nontemporal_load(qp + 1);
      // A source: 8 fp32 x values for this lane's fragment (L2-hot)
      f32x4 x0 = *(const f32x4*)(xbase + ii * 32);
      f32x4 x1 = *(const f32x4*)(xbase + ii * 32 + 4);
      float s   = (i < 4) ? sA[i] : sB[i - 4];
      float m8s = -8.f * s;
      union { uint32_t u[4]; bf16x8 v; } A, B;
      // pack x -> bf16 (round-half-up), two halves per dword via v_perm
      uint32_t a0 = __float_as_uint(x0.x) + 0x8000u;
      uint32_t a1 = __float_as_uint(x0.y) + 0x8000u;
      uint32_t a2 = __float_as_uint(x0.z) + 0x8000u;
      uint32_t a3 = __float_as_uint(x0.w) + 0x8000u;
      uint32_t a4 = __float_as_uint(x1.x) + 0x8000u;
      uint32_t a5 = __float_as_uint(x1.y) + 0x8000u;
      uint32_t a6 = __float_as_uint(x1.z) + 0x8000u;
      uint32_t a7 = __float_as_uint(x1.w) + 0x8000u;
      A.u[0] = __builtin_amdgcn_perm(a1, a0, 0x07060302u);
      A.u[1] = __builtin_amdgcn_perm(a3, a2, 0x07060302u);
      A.u[2] = __builtin_amdgcn_perm(a5, a4, 0x07060302u);
      A.u[3] = __builtin_amdgcn_perm(a7, a6, 0x07060302u);
      // dequant: w = s*q - 8s (exact in fp32), truncate-pack to bf16
      uint32_t w0 = __float_as_uint(fmaf((float)q0.x, s, m8s));
      uint32_t w1 = __float_as_uint(fmaf((float)q0.y, s, m8s));
      uint32_t w2 = __float_as_uint(fmaf((float)q0.z, s, m8s));
      uint32_t w3 = __float_as_uint(fmaf((float)q0.w, s, m8s));
      uint32_t w4 = __float_as_uint(fmaf((float)q1.x, s, m8s));
      uint32_t w5 = __float_as_uint(fmaf((float)q1.y, s, m8s));
      uint32_t w6 = __float_as_uint(fmaf((float)q1.z, s, m8s));
      uint32_t w7 = __float_as_uint(fmaf((float)q1.w, s, m8s));
      B.u[0] = __builtin_amdgcn_perm(w1, w0, 0x07060302u);
      B.u[1] = __builtin_amdgcn_perm(w3, w2, 0x07060302u);
      B.u[2] = __builtin_amdgcn_perm(w5, w4, 0x07060302u);
      B.u[3] = __builtin_amdgcn_perm(w7, w6, 0x07060302u);
      acc = __builtin_amdgcn_mfma_f32_16x16x32_bf16(A.v, B.v, acc, 0, 0, 0);
    }
  }

  // Cross-wave combine. C/D layout: lane holds D[row=kr*4+r][col], col=lane&15.
  __shared__ float red[4][256];
#pragma unroll
  for (int r = 0; r < 4; ++r) {
    int t = kr * 4 + r;
    red[wave][t * 16 + col] = acc[r];
  }
  __syncthreads();

  float v = red[0][tid] + red[1][tid] + red[2][tid] + red[3][tid];
  int t = tid >> 4;            // token 0..15
  int o = ob + (tid & 15);     // output feature
  out[(size_t)t * OUT_F + o] = v + bias[o];
}

// ---------------------------------------------------------------------------
extern "C" void kernel_launch(void* const* d_in, const int* in_sizes, int n_in,
                              void* d_out, int out_size, void* d_ws, size_t ws_size,
                              hipStream_t stream) {
  const float* x      = (const float*)d_in[0];
  const int*   qw     = (const int*)d_in[1];
  const float* scales = (const float*)d_in[2];
  const float* bias   = (const float*)d_in[3];
  float* out = (float*)d_out;

  // 688 tiles of 16 outputs; full K per block; no ws, no atomics.
  qgemm_kernel<<<688, 256, 0, stream>>>(x, qw, scales, bias, out);
}

// Round 4
// 251.425 us; speedup vs baseline: 1.0629x; 1.0629x over previous
//
#include <hip/hip_runtime.h>
#include <stdint.h>

// Q4_0 dequant-GEMM: y[t,o] = sum_k x[t,k] * s[o,k/32]*(q[o,k]-8) + bias[o]
// M=16 tokens, K=4096, N=11008. HBM-bound: 172 MiB int32 qweight stream,
// floor ~29 us at 6.3 TB/s.
//
// R4 theory: R2/R3 were LATENCY-bound on the qweight stream (register-landing
// loads cap in-flight bytes at a few KB/CU; need ~9 KB/CU by Little's law).
// Fix: stage qweight via __builtin_amdgcn_global_load_lds (width 16) - no
// VGPR landing, so each wave parks its ENTIRE K-chunk (8 KB) in the vmcnt
// queue up front. One __syncthreads provides the vmcnt(0) drain (correctness
// by construction, m97-style). K-split x8 -> 5504 blocks, 4 resident/CU
// (36 KB LDS), 16 waves/CU => ~100+ KB in flight per CU. Epilogue: LDS
// cross-wave combine + relaxed agent atomicAdd; d_out zeroed by a memset node.

typedef __attribute__((ext_vector_type(8))) short bf16x8;  // 8 bf16 (4 VGPRs)
typedef __attribute__((ext_vector_type(4))) float f32x4;

#define OUT_F 11008
#define IN_F  4096
#define NB    128      // quant blocks along K
#define KSPLIT 8
#define QB_BLK (NB / KSPLIT)   // 16 quant-blocks per block
#define QB_WV  (QB_BLK / 4)    // 4 quant-blocks (= MFMAs) per wave

__global__ __launch_bounds__(256, 4)
void qgemm_kernel(const float* __restrict__ x,
                  const int* __restrict__ qw,
                  const float* __restrict__ scales,
                  const float* __restrict__ bias,
                  float* __restrict__ out) {
  // Staging: 4 waves x 4 slots x 2048 B (one slot = one quant-block for all
  // 64 lanes: part0 = lanes' first 16 B, part1 = lanes' second 16 B).
  __shared__ uint4 stage[4][QB_WV][128];   // 32 KB
  __shared__ float red[4][256];            // 4 KB

  const int bid  = blockIdx.x;
  const int kq   = bid & (KSPLIT - 1);
  const int ob   = (bid >> 3) << 4;        // 16 output features per tile
  const int tid  = threadIdx.x;
  const int wave = tid >> 6;
  const int lane = tid & 63;
  const int col  = lane & 15;              // output row (B) / token (A)
  const int kr   = lane >> 4;              // k sub-chunk 0..3

  const int kb0 = kq * QB_BLK + wave * QB_WV;  // first quant-block index

  // Per-lane global source: row (ob+col), quant-block kb0+s, 32 B sub-chunk kr.
  const char* qrow = (const char*)(qw + (size_t)(ob + col) * IN_F)
                   + (size_t)kb0 * 128 + kr * 32;

  // Issue the whole q-stage: 8 x global_load_lds_dwordx4, no VGPR landing.
  // LDS dest is wave-uniform base + lane*16 (lane order == readback order).
#pragma unroll
  for (int s = 0; s < QB_WV; ++s) {
    __builtin_amdgcn_global_load_lds(
        (const __attribute__((address_space(1))) void*)(qrow + s * 128),
        (__attribute__((address_space(3))) void*)(&stage[wave][s][0]),
        16, 0, 0);
    __builtin_amdgcn_global_load_lds(
        (const __attribute__((address_space(1))) void*)(qrow + s * 128 + 16),
        (__attribute__((address_space(3))) void*)(&stage[wave][s][64]),
        16, 0, 0);
  }

  // x prefetch (L2-hot, 32 B/lane/iter) + per-lane scales, before the barrier
  // so their latency overlaps the staging drain.
  const float* xb = x + col * IN_F + kb0 * 32 + kr * 8;
  f32x4 xv[QB_WV][2];
#pragma unroll
  for (int s = 0; s < QB_WV; ++s) {
    xv[s][0] = *(const f32x4*)(xb + s * 32);
    xv[s][1] = *(const f32x4*)(xb + s * 32 + 4);
  }
  f32x4 sv = *(const f32x4*)(scales + (ob + col) * NB + kb0);

  __syncthreads();  // vmcnt(0) drain: staging + x + scales all complete

  f32x4 acc = {0.f, 0.f, 0.f, 0.f};
#pragma unroll
  for (int s = 0; s < QB_WV; ++s) {
    // readback: this lane's 32 B of quants (2 x ds_read_b128, conflict-free)
    uint4 q0 = stage[wave][s][lane];
    uint4 q1 = stage[wave][s][64 + lane];
    float sc  = sv[s];
    float m8s = -8.f * sc;
    union { uint32_t u[4]; bf16x8 v; } A, B;
    // pack x -> bf16 (round-half-up) via v_perm
    uint32_t a0 = __float_as_uint(xv[s][0].x) + 0x8000u;
    uint32_t a1 = __float_as_uint(xv[s][0].y) + 0x8000u;
    uint32_t a2 = __float_as_uint(xv[s][0].z) + 0x8000u;
    uint32_t a3 = __float_as_uint(xv[s][0].w) + 0x8000u;
    uint32_t a4 = __float_as_uint(xv[s][1].x) + 0x8000u;
    uint32_t a5 = __float_as_uint(xv[s][1].y) + 0x8000u;
    uint32_t a6 = __float_as_uint(xv[s][1].z) + 0x8000u;
    uint32_t a7 = __float_as_uint(xv[s][1].w) + 0x8000u;
    A.u[0] = __builtin_amdgcn_perm(a1, a0, 0x07060302u);
    A.u[1] = __builtin_amdgcn_perm(a3, a2, 0x07060302u);
    A.u[2] = __builtin_amdgcn_perm(a5, a4, 0x07060302u);
    A.u[3] = __builtin_amdgcn_perm(a7, a6, 0x07060302u);
    // dequant: w = s*q - 8s (exact in fp32), truncate-pack to bf16
    uint32_t w0 = __float_as_uint(fmaf((float)(int)q0.x, sc, m8s));
    uint32_t w1 = __float_as_uint(fmaf((float)(int)q0.y, sc, m8s));
    uint32_t w2 = __float_as_uint(fmaf((float)(int)q0.z, sc, m8s));
    uint32_t w3 = __float_as_uint(fmaf((float)(int)q0.w, sc, m8s));
    uint32_t w4 = __float_as_uint(fmaf((float)(int)q1.x, sc, m8s));
    uint32_t w5 = __float_as_uint(fmaf((float)(int)q1.y, sc, m8s));
    uint32_t w6 = __float_as_uint(fmaf((float)(int)q1.z, sc, m8s));
    uint32_t w7 = __float_as_uint(fmaf((float)(int)q1.w, sc, m8s));
    B.u[0] = __builtin_amdgcn_perm(w1, w0, 0x07060302u);
    B.u[1] = __builtin_amdgcn_perm(w3, w2, 0x07060302u);
    B.u[2] = __builtin_amdgcn_perm(w5, w4, 0x07060302u);
    B.u[3] = __builtin_amdgcn_perm(w7, w6, 0x07060302u);
    acc = __builtin_amdgcn_mfma_f32_16x16x32_bf16(A.v, B.v, acc, 0, 0, 0);
  }

  // Cross-wave combine. C/D layout: lane holds D[row=kr*4+r][col].
#pragma unroll
  for (int r = 0; r < 4; ++r)
    red[wave][(kr * 4 + r) * 16 + col] = acc[r];
  __syncthreads();

  float v = red[0][tid] + red[1][tid] + red[2][tid] + red[3][tid];
  int t = tid >> 4;
  int o = ob + (tid & 15);
  if (kq == 0) v += bias[o];
  __hip_atomic_fetch_add(out + (size_t)t * OUT_F + o, v, __ATOMIC_RELAXED,
                         __HIP_MEMORY_SCOPE_AGENT);
}

// ---------------------------------------------------------------------------
extern "C" void kernel_launch(void* const* d_in, const int* in_sizes, int n_in,
                              void* d_out, int out_size, void* d_ws, size_t ws_size,
                              hipStream_t stream) {
  const float* x      = (const float*)d_in[0];
  const int*   qw     = (const int*)d_in[1];
  const float* scales = (const float*)d_in[2];
  const float* bias   = (const float*)d_in[3];
  float* out = (float*)d_out;

  // zero-init for the atomic K-split accumulation (graph-capturable node)
  hipMemsetAsync(out, 0, (size_t)out_size * sizeof(float), stream);
  // 688 output tiles x 8 K-splits
  qgemm_kernel<<<688 * KSPLIT, 256, 0, stream>>>(x, qw, scales, bias, out);
}